// Round 6
// baseline (527.577 us; speedup 1.0000x reference)
//
#include <hip/hip_runtime.h>
#include <hip/hip_bf16.h>

#define NNODE 1024
#define DIM 128
#define HEADS 8
#define DK 16
#define EDIM 16
#define BN 8               // target nodes per attn block
#define MR 32              // source rows per block (2 sub-chunks of 16)
#define MC 16              // rows per sub-chunk
#define KV_ROW 160         // k/v LDS row stride dwords = 8 h * 20
#define H_STRIDE 20        // 20h mod 32 distinct for h=0..7 -> conflict-free reads
#define EF_ROW 20          // ef m-stride (dwords)
#define EF_NSTR 324        // ef n-stride = 16*20+4: bank skew +4 per n -> conflict-free
#define LOG2E 1.44269504f

// ---------------- Kernel 1: LayerNorm + QKV projection ----------------
__global__ __launch_bounds__(384)
void ln_qkv_kernel(const float* __restrict__ x,
                   const float* __restrict__ Wq, const float* __restrict__ bq,
                   const float* __restrict__ Wk, const float* __restrict__ bk,
                   const float* __restrict__ Wv, const float* __restrict__ bv,
                   const float* __restrict__ gamma, const float* __restrict__ beta,
                   float* __restrict__ qg, float* __restrict__ kg, float* __restrict__ vg) {
    const int n = blockIdx.x;
    const int t = threadIdx.x;
    __shared__ float hrow[DIM];
    __shared__ float part[4];

    float xv = 0.f;
    if (t < 128) {
        xv = x[n * DIM + t];
        float v = xv;
        #pragma unroll
        for (int off = 32; off >= 1; off >>= 1) v += __shfl_xor(v, off);
        if ((t & 63) == 0) part[t >> 6] = v;
    }
    __syncthreads();
    const float mu = (part[0] + part[1]) * (1.0f / DIM);
    const float dx = xv - mu;
    if (t < 128) {
        float v = dx * dx;
        #pragma unroll
        for (int off = 32; off >= 1; off >>= 1) v += __shfl_xor(v, off);
        if ((t & 63) == 0) part[2 + (t >> 6)] = v;
    }
    __syncthreads();
    if (t < 128) {
        const float var = (part[2] + part[3]) * (1.0f / DIM);
        hrow[t] = dx * rsqrtf(var + 1e-5f) * gamma[t] + beta[t];
    }
    __syncthreads();

    const int which = t >> 7;          // 0,1,2 -> q,k,v (wave-uniform)
    const int col = t & 127;
    const float* W = (which == 0) ? Wq : (which == 1) ? Wk : Wv;
    const float* b = (which == 0) ? bq : (which == 1) ? bk : bv;
    float* o       = (which == 0) ? qg : (which == 1) ? kg : vg;
    float acc = b[col];
    #pragma unroll 16
    for (int i = 0; i < DIM; ++i) acc = fmaf(hrow[i], W[i * DIM + col], acc);
    o[n * DIM + col] = acc;
}

// ---------------- Kernel 2: attention partials, ds_add block-reduce, atomics out ----------------
// grid = (1024/BN)*32 = 4096 blocks; 256 threads = (s: t>>5, np: (t>>3)&3, h: t&7)
// Block covers nodes [n0,n0+8) x m in [mb,mb+32), processed as 2 sub-chunks of 16
// so LDS stays under 40 KB -> 4 blocks/CU. Thread handles n = np and n = np+4.
// All register-array indices compile-time constant (round-4 lesson).
__global__ __launch_bounds__(256, 4)
void attn_kernel(const float* __restrict__ qg, const float* __restrict__ kg,
                 const float* __restrict__ vg, const float* __restrict__ ef,
                 const int* __restrict__ mask,
                 const float* __restrict__ Wae, const float* __restrict__ bae,
                 float* __restrict__ acc) {
    const int t = threadIdx.x;
    const int s  = t >> 5;        // 0..7 m sub-slot
    const int np = (t >> 3) & 3;  // n-pair id
    const int h  = t & 7;         // head
    const int lane = t & 63;
    const int bx = blockIdx.x;
    const int n0 = (bx >> 5) * BN;
    const int mb = (bx & 31) * MR;

    __shared__ float ef_lds[BN * EF_NSTR];      // 10.4 KB, skewed layout
    __shared__ float k_lds[MC * KV_ROW];        // 10.25 KB
    __shared__ float v_lds[MC * KV_ROW];        // 10.25 KB
    __shared__ float red[BN * HEADS * 33];      // 8.45 KB block accumulator (ds_add)
    __shared__ int   mk_lds[BN * 18];

    // zero the block accumulator (published by the first chunk's barrier)
    for (int u = t; u < BN * HEADS * 33; u += 256) red[u] = 0.f;

    // --- per-thread constants (global, L2-hot) ---
    float qreg[2][DK];
    #pragma unroll
    for (int hf = 0; hf < 2; ++hf) {
        const float* qp = qg + (size_t)(n0 + np + 4 * hf) * DIM + h * DK;
        #pragma unroll
        for (int d4 = 0; d4 < 4; ++d4) {
            const float4 qv = *(const float4*)(qp + d4 * 4);
            qreg[hf][d4 * 4 + 0] = qv.x; qreg[hf][d4 * 4 + 1] = qv.y;
            qreg[hf][d4 * 4 + 2] = qv.z; qreg[hf][d4 * 4 + 3] = qv.w;
        }
    }
    float waec[EDIM];
    #pragma unroll
    for (int e = 0; e < EDIM; ++e) waec[e] = Wae[e * HEADS + h] * LOG2E;
    const float baeh = bae[h] * LOG2E;

    float sl[2] = {0.f, 0.f};
    float accv[2][DK], accT[2][EDIM];
    #pragma unroll
    for (int hf = 0; hf < 2; ++hf) {
        #pragma unroll
        for (int d = 0; d < DK; ++d) accv[hf][d] = 0.f;
        #pragma unroll
        for (int e = 0; e < EDIM; ++e) accT[hf][e] = 0.f;
    }

    #pragma unroll
    for (int c = 0; c < 2; ++c) {
        const int mcb = mb + c * MC;
        if (c) __syncthreads();            // previous chunk's LDS consumers done

        // --- ef stage: 8n x 16m x 4q4 = 512 float4, 2/thread, skewed layout ---
        #pragma unroll
        for (int r = 0; r < 2; ++r) {
            const int idx = t + 256 * r;   // 0..511
            const int nn = idx >> 6;
            const int mm = (idx >> 2) & 15;
            const int q4 = idx & 3;
            const float4 ev = *(const float4*)(ef + ((size_t)(n0 + nn) * NNODE + mcb + mm) * EDIM + q4 * 4);
            *(float4*)&ef_lds[nn * EF_NSTR + mm * EF_ROW + q4 * 4] = ev;
        }
        // --- k/v stage into padded [mm][h][20] layout: 512 float4 each, 2/thread ---
        #pragma unroll
        for (int r = 0; r < 2; ++r) {
            const int idx = t + 256 * r;   // 0..511
            const int mm = idx >> 5, c4 = idx & 31;
            const int hh = c4 >> 2, d4 = c4 & 3;
            const float4 kq = *(const float4*)(kg + (size_t)(mcb + mm) * DIM + c4 * 4);
            const float4 vq = *(const float4*)(vg + (size_t)(mcb + mm) * DIM + c4 * 4);
            *(float4*)&k_lds[mm * KV_ROW + hh * H_STRIDE + d4 * 4] = kq;
            *(float4*)&v_lds[mm * KV_ROW + hh * H_STRIDE + d4 * 4] = vq;
        }
        // --- mask stage: 8n x 16m ---
        if (t < BN * MC) {
            const int nn = t >> 4, mm = t & 15;
            mk_lds[nn * 18 + mm] = mask[(size_t)(n0 + nn) * NNODE + mcb + mm];
        }
        __syncthreads();

        // --- compute: 2 m per thread (m = 8j+s), n-pair per m; all indices static ---
        #pragma unroll
        for (int j = 0; j < 2; ++j) {
            const int m = j * 8 + s;
            float kk[DK], vv[DK];
            const float* kp = &k_lds[m * KV_ROW + h * H_STRIDE];
            const float* vp = &v_lds[m * KV_ROW + h * H_STRIDE];
            #pragma unroll
            for (int d4 = 0; d4 < 4; ++d4) {
                const float4 k4 = *(const float4*)(kp + d4 * 4);
                kk[d4 * 4 + 0] = k4.x; kk[d4 * 4 + 1] = k4.y;
                kk[d4 * 4 + 2] = k4.z; kk[d4 * 4 + 3] = k4.w;
                const float4 v4 = *(const float4*)(vp + d4 * 4);
                vv[d4 * 4 + 0] = v4.x; vv[d4 * 4 + 1] = v4.y;
                vv[d4 * 4 + 2] = v4.z; vv[d4 * 4 + 3] = v4.w;
            }
            #pragma unroll
            for (int hf = 0; hf < 2; ++hf) {
                const int n = np + 4 * hf;
                const float* ep = &ef_lds[n * EF_NSTR + m * EF_ROW];
                float efv[EDIM];
                #pragma unroll
                for (int e4 = 0; e4 < 4; ++e4) {   // STATIC e4 (skew handles banks)
                    const float4 ev = *(const float4*)(ep + e4 * 4);
                    efv[e4 * 4 + 0] = ev.x; efv[e4 * 4 + 1] = ev.y;
                    efv[e4 * 4 + 2] = ev.z; efv[e4 * 4 + 3] = ev.w;
                }
                float bias = baeh, dot = 0.f;
                #pragma unroll
                for (int e = 0; e < EDIM; ++e) bias = fmaf(efv[e], waec[e], bias);
                #pragma unroll
                for (int d = 0; d < DK; ++d) dot = fmaf(qreg[hf][d], kk[d], dot);
                const float lg = fmaf(dot, 0.25f * LOG2E, bias);
                const float p = mk_lds[n * 18 + m] ? __builtin_amdgcn_exp2f(lg) : 0.f;
                sl[hf] += p;
                #pragma unroll
                for (int d = 0; d < DK; ++d) accv[hf][d] = fmaf(p, vv[d], accv[hf][d]);
                #pragma unroll
                for (int e = 0; e < EDIM; ++e) accT[hf][e] = fmaf(p, efv[e], accT[hf][e]);
            }
        }
    }

    // --- reduce s-pairs within wave (lane ^ 32), then ds_add into block accumulator ---
    // red layout [n(8)][h(8)][33]: ds_add addr = 264n + 33h + idx -> banks 8np+h+...,
    // all 32 active lanes distinct banks, conflict-free.
    #pragma unroll
    for (int hf = 0; hf < 2; ++hf) {
        sl[hf] += __shfl_xor(sl[hf], 32);
        #pragma unroll
        for (int d = 0; d < DK; ++d) accv[hf][d] += __shfl_xor(accv[hf][d], 32);
        #pragma unroll
        for (int e = 0; e < EDIM; ++e) accT[hf][e] += __shfl_xor(accT[hf][e], 32);
    }
    if (lane < 32) {
        #pragma unroll
        for (int hf = 0; hf < 2; ++hf) {
            float* rp = &red[((np + 4 * hf) * 8 + h) * 33];
            atomicAdd(&rp[0], sl[hf]);
            #pragma unroll
            for (int d = 0; d < DK; ++d) atomicAdd(&rp[1 + d], accv[hf][d]);
            #pragma unroll
            for (int e = 0; e < EDIM; ++e) atomicAdd(&rp[17 + e], accT[hf][e]);
        }
    }
    __syncthreads();
    // --- one global atomicAdd per reduced value; acc layout matches red layout ---
    for (int u = t; u < BN * HEADS * 33; u += 256)
        atomicAdd(&acc[(size_t)n0 * HEADS * 33 + u], red[u]);
}

// ---------------- Kernel 3: epilogue (Wve, normalize, Wo, residual) ----------------
__global__ __launch_bounds__(128)
void final_kernel(const float* __restrict__ acc,
                  const float* __restrict__ Wve, const float* __restrict__ bve,
                  const float* __restrict__ x,
                  const float* __restrict__ Wo, const float* __restrict__ bo,
                  float* __restrict__ out) {
    const int n = blockIdx.x, t = threadIdx.x;
    __shared__ float ab[HEADS * 33];
    __shared__ float orow[DIM];
    for (int u = t; u < HEADS * 33; u += 128) ab[u] = acc[(size_t)n * HEADS * 33 + u];
    __syncthreads();
    const int col = t, hh = col >> 4, dd = col & 15;
    const float slv = ab[hh * 33];
    float acc2 = 0.f;
    #pragma unroll
    for (int e = 0; e < EDIM; ++e) acc2 = fmaf(ab[hh * 33 + 17 + e], Wve[e * DIM + col], acc2);
    orow[col] = (ab[hh * 33 + 1 + dd] + acc2) / slv + bve[col];
    __syncthreads();
    float o = bo[col] + x[(size_t)n * DIM + col];
    #pragma unroll 16
    for (int i = 0; i < DIM; ++i) o = fmaf(orow[i], Wo[i * DIM + col], o);
    out[(size_t)n * DIM + col] = o;
}

extern "C" void kernel_launch(void* const* d_in, const int* in_sizes, int n_in,
                              void* d_out, int out_size, void* d_ws, size_t ws_size,
                              hipStream_t stream) {
    const float* x     = (const float*)d_in[0];
    const float* ef    = (const float*)d_in[1];
    const int*   mask  = (const int*)d_in[2];
    const float* Wq    = (const float*)d_in[3];
    const float* bq    = (const float*)d_in[4];
    const float* Wk    = (const float*)d_in[5];
    const float* bk    = (const float*)d_in[6];
    const float* Wv    = (const float*)d_in[7];
    const float* bv    = (const float*)d_in[8];
    const float* Wae   = (const float*)d_in[9];
    const float* bae   = (const float*)d_in[10];
    const float* Wve   = (const float*)d_in[11];
    const float* bve   = (const float*)d_in[12];
    const float* Wo    = (const float*)d_in[13];
    const float* bo    = (const float*)d_in[14];
    const float* gamma = (const float*)d_in[15];
    const float* beta  = (const float*)d_in[16];

    float* ws = (float*)d_ws;
    float* accb = ws;                                   // 1024*8*33 = 270336 f32
    float* qg   = ws + 270336;
    float* kg   = qg + (size_t)NNODE * DIM;
    float* vg   = kg + (size_t)NNODE * DIM;

    hipMemsetAsync(accb, 0, (size_t)NNODE * HEADS * 33 * sizeof(float), stream);
    ln_qkv_kernel<<<NNODE, 384, 0, stream>>>(x, Wq, bq, Wk, bk, Wv, bv, gamma, beta, qg, kg, vg);
    attn_kernel<<<(NNODE / BN) * 32, 256, 0, stream>>>(qg, kg, vg, ef, mask, Wae, bae, accb);
    final_kernel<<<NNODE, 128, 0, stream>>>(accb, Wve, bve, x, Wo, bo, (float*)d_out);
}

// Round 7
// 355.346 us; speedup vs baseline: 1.4847x; 1.4847x over previous
//
#include <hip/hip_runtime.h>
#include <hip/hip_bf16.h>

#define NNODE 1024
#define DIM 128
#define HEADS 8
#define DK 16
#define EDIM 16
#define BN 8               // target nodes per attn block
#define MR 32              // source rows per block (2 sub-chunks of 16)
#define MC 16              // rows per sub-chunk
#define KV_ROW 160         // k/v LDS row stride dwords = 8 h * 20
#define H_STRIDE 20        // 20h mod 32 distinct for h=0..7 -> conflict-free reads
#define EF_ROW 20          // ef m-stride (dwords)
#define EF_NSTR 324        // ef n-stride = 16*20+4: bank skew +4 per n -> conflict-free
#define LOG2E 1.44269504f

// ---------------- Kernel 1: LayerNorm + QKV projection ----------------
__global__ __launch_bounds__(384)
void ln_qkv_kernel(const float* __restrict__ x,
                   const float* __restrict__ Wq, const float* __restrict__ bq,
                   const float* __restrict__ Wk, const float* __restrict__ bk,
                   const float* __restrict__ Wv, const float* __restrict__ bv,
                   const float* __restrict__ gamma, const float* __restrict__ beta,
                   float* __restrict__ qg, float* __restrict__ kg, float* __restrict__ vg) {
    const int n = blockIdx.x;
    const int t = threadIdx.x;
    __shared__ float hrow[DIM];
    __shared__ float part[4];

    float xv = 0.f;
    if (t < 128) {
        xv = x[n * DIM + t];
        float v = xv;
        #pragma unroll
        for (int off = 32; off >= 1; off >>= 1) v += __shfl_xor(v, off);
        if ((t & 63) == 0) part[t >> 6] = v;
    }
    __syncthreads();
    const float mu = (part[0] + part[1]) * (1.0f / DIM);
    const float dx = xv - mu;
    if (t < 128) {
        float v = dx * dx;
        #pragma unroll
        for (int off = 32; off >= 1; off >>= 1) v += __shfl_xor(v, off);
        if ((t & 63) == 0) part[2 + (t >> 6)] = v;
    }
    __syncthreads();
    if (t < 128) {
        const float var = (part[2] + part[3]) * (1.0f / DIM);
        hrow[t] = dx * rsqrtf(var + 1e-5f) * gamma[t] + beta[t];
    }
    __syncthreads();

    const int which = t >> 7;          // 0,1,2 -> q,k,v (wave-uniform)
    const int col = t & 127;
    const float* W = (which == 0) ? Wq : (which == 1) ? Wk : Wv;
    const float* b = (which == 0) ? bq : (which == 1) ? bk : bv;
    float* o       = (which == 0) ? qg : (which == 1) ? kg : vg;
    float acc = b[col];
    #pragma unroll 16
    for (int i = 0; i < DIM; ++i) acc = fmaf(hrow[i], W[i * DIM + col], acc);
    o[n * DIM + col] = acc;
}

// ---------------- Kernel 2: attention partials, ds_add block-reduce, atomics out ----------------
// grid = (1024/BN)*32 = 4096 blocks; 256 threads = (s: t>>5, np: (t>>3)&3, h: t&7)
// Block covers nodes [n0,n0+8) x m in [mb,mb+32), as 2 sub-chunks of 16 (LDS < 40 KB
// -> 4 blocks/CU by LDS). Thread handles n = np and n = np+4.
// __launch_bounds__(256,2): live accumulator state is ~116 VGPRs; round 6 proved that
// capping to 4 waves/EU (128) made the allocator clamp to 64 and spill 1.15 GB/launch.
// At ~116-128 VGPR the HW still gives 4 waves/SIMD, so occupancy is unchanged.
__global__ __launch_bounds__(256, 2)
void attn_kernel(const float* __restrict__ qg, const float* __restrict__ kg,
                 const float* __restrict__ vg, const float* __restrict__ ef,
                 const int* __restrict__ mask,
                 const float* __restrict__ Wae, const float* __restrict__ bae,
                 float* __restrict__ acc) {
    const int t = threadIdx.x;
    const int s  = t >> 5;        // 0..7 m sub-slot
    const int np = (t >> 3) & 3;  // n-pair id
    const int h  = t & 7;         // head
    const int lane = t & 63;
    const int bx = blockIdx.x;
    const int n0 = (bx >> 5) * BN;
    const int mb = (bx & 31) * MR;

    __shared__ float ef_lds[BN * EF_NSTR];      // 10.4 KB, skewed layout
    __shared__ float k_lds[MC * KV_ROW];        // 10.25 KB
    __shared__ float v_lds[MC * KV_ROW];        // 10.25 KB
    __shared__ float red[BN * HEADS * 33];      // 8.45 KB block accumulator (ds_add)
    __shared__ int   mk_lds[BN * 18];

    // zero the block accumulator (published by the first chunk's barrier)
    for (int u = t; u < BN * HEADS * 33; u += 256) red[u] = 0.f;

    // --- per-thread constants (global, L2-hot) ---
    float qreg[2][DK];
    #pragma unroll
    for (int hf = 0; hf < 2; ++hf) {
        const float* qp = qg + (size_t)(n0 + np + 4 * hf) * DIM + h * DK;
        #pragma unroll
        for (int d4 = 0; d4 < 4; ++d4) {
            const float4 qv = *(const float4*)(qp + d4 * 4);
            qreg[hf][d4 * 4 + 0] = qv.x; qreg[hf][d4 * 4 + 1] = qv.y;
            qreg[hf][d4 * 4 + 2] = qv.z; qreg[hf][d4 * 4 + 3] = qv.w;
        }
    }
    float waec[EDIM];
    #pragma unroll
    for (int e = 0; e < EDIM; ++e) waec[e] = Wae[e * HEADS + h] * LOG2E;
    const float baeh = bae[h] * LOG2E;

    float sl[2] = {0.f, 0.f};
    float accv[2][DK], accT[2][EDIM];
    #pragma unroll
    for (int hf = 0; hf < 2; ++hf) {
        #pragma unroll
        for (int d = 0; d < DK; ++d) accv[hf][d] = 0.f;
        #pragma unroll
        for (int e = 0; e < EDIM; ++e) accT[hf][e] = 0.f;
    }

    #pragma unroll
    for (int c = 0; c < 2; ++c) {
        const int mcb = mb + c * MC;
        if (c) __syncthreads();            // previous chunk's LDS consumers done

        // --- ef stage: 8n x 16m x 4q4 = 512 float4, 2/thread, skewed layout ---
        #pragma unroll
        for (int r = 0; r < 2; ++r) {
            const int idx = t + 256 * r;   // 0..511
            const int nn = idx >> 6;
            const int mm = (idx >> 2) & 15;
            const int q4 = idx & 3;
            const float4 ev = *(const float4*)(ef + ((size_t)(n0 + nn) * NNODE + mcb + mm) * EDIM + q4 * 4);
            *(float4*)&ef_lds[nn * EF_NSTR + mm * EF_ROW + q4 * 4] = ev;
        }
        // --- k/v stage into padded [mm][h][20] layout: 512 float4 each, 2/thread ---
        #pragma unroll
        for (int r = 0; r < 2; ++r) {
            const int idx = t + 256 * r;   // 0..511
            const int mm = idx >> 5, c4 = idx & 31;
            const int hh = c4 >> 2, d4 = c4 & 3;
            const float4 kq = *(const float4*)(kg + (size_t)(mcb + mm) * DIM + c4 * 4);
            const float4 vq = *(const float4*)(vg + (size_t)(mcb + mm) * DIM + c4 * 4);
            *(float4*)&k_lds[mm * KV_ROW + hh * H_STRIDE + d4 * 4] = kq;
            *(float4*)&v_lds[mm * KV_ROW + hh * H_STRIDE + d4 * 4] = vq;
        }
        // --- mask stage: 8n x 16m ---
        if (t < BN * MC) {
            const int nn = t >> 4, mm = t & 15;
            mk_lds[nn * 18 + mm] = mask[(size_t)(n0 + nn) * NNODE + mcb + mm];
        }
        __syncthreads();

        // --- compute: 2 m per thread (m = 8j+s), n-pair per m; all indices static ---
        #pragma unroll
        for (int j = 0; j < 2; ++j) {
            const int m = j * 8 + s;
            float kk[DK], vv[DK];
            const float* kp = &k_lds[m * KV_ROW + h * H_STRIDE];
            const float* vp = &v_lds[m * KV_ROW + h * H_STRIDE];
            #pragma unroll
            for (int d4 = 0; d4 < 4; ++d4) {
                const float4 k4 = *(const float4*)(kp + d4 * 4);
                kk[d4 * 4 + 0] = k4.x; kk[d4 * 4 + 1] = k4.y;
                kk[d4 * 4 + 2] = k4.z; kk[d4 * 4 + 3] = k4.w;
                const float4 v4 = *(const float4*)(vp + d4 * 4);
                vv[d4 * 4 + 0] = v4.x; vv[d4 * 4 + 1] = v4.y;
                vv[d4 * 4 + 2] = v4.z; vv[d4 * 4 + 3] = v4.w;
            }
            #pragma unroll
            for (int hf = 0; hf < 2; ++hf) {
                const int n = np + 4 * hf;
                const float* ep = &ef_lds[n * EF_NSTR + m * EF_ROW];
                float efv[EDIM];
                #pragma unroll
                for (int e4 = 0; e4 < 4; ++e4) {   // STATIC e4 (skew handles banks)
                    const float4 ev = *(const float4*)(ep + e4 * 4);
                    efv[e4 * 4 + 0] = ev.x; efv[e4 * 4 + 1] = ev.y;
                    efv[e4 * 4 + 2] = ev.z; efv[e4 * 4 + 3] = ev.w;
                }
                float bias = baeh, dot = 0.f;
                #pragma unroll
                for (int e = 0; e < EDIM; ++e) bias = fmaf(efv[e], waec[e], bias);
                #pragma unroll
                for (int d = 0; d < DK; ++d) dot = fmaf(qreg[hf][d], kk[d], dot);
                const float lg = fmaf(dot, 0.25f * LOG2E, bias);
                const float p = mk_lds[n * 18 + m] ? __builtin_amdgcn_exp2f(lg) : 0.f;
                sl[hf] += p;
                #pragma unroll
                for (int d = 0; d < DK; ++d) accv[hf][d] = fmaf(p, vv[d], accv[hf][d]);
                #pragma unroll
                for (int e = 0; e < EDIM; ++e) accT[hf][e] = fmaf(p, efv[e], accT[hf][e]);
            }
        }
    }

    // --- reduce s-pairs within wave (lane ^ 32), then ds_add into block accumulator ---
    // red layout [n(8)][h(8)][33]: ds_add addr = 264n + 33h + idx -> banks 8np+h+...,
    // all 32 active lanes distinct banks, conflict-free.
    #pragma unroll
    for (int hf = 0; hf < 2; ++hf) {
        sl[hf] += __shfl_xor(sl[hf], 32);
        #pragma unroll
        for (int d = 0; d < DK; ++d) accv[hf][d] += __shfl_xor(accv[hf][d], 32);
        #pragma unroll
        for (int e = 0; e < EDIM; ++e) accT[hf][e] += __shfl_xor(accT[hf][e], 32);
    }
    if (lane < 32) {
        #pragma unroll
        for (int hf = 0; hf < 2; ++hf) {
            float* rp = &red[((np + 4 * hf) * 8 + h) * 33];
            atomicAdd(&rp[0], sl[hf]);
            #pragma unroll
            for (int d = 0; d < DK; ++d) atomicAdd(&rp[1 + d], accv[hf][d]);
            #pragma unroll
            for (int e = 0; e < EDIM; ++e) atomicAdd(&rp[17 + e], accT[hf][e]);
        }
    }
    __syncthreads();
    // --- one global atomicAdd per reduced value; acc layout matches red layout ---
    for (int u = t; u < BN * HEADS * 33; u += 256)
        atomicAdd(&acc[(size_t)n0 * HEADS * 33 + u], red[u]);
}

// ---------------- Kernel 3: epilogue (Wve, normalize, Wo, residual) ----------------
__global__ __launch_bounds__(128)
void final_kernel(const float* __restrict__ acc,
                  const float* __restrict__ Wve, const float* __restrict__ bve,
                  const float* __restrict__ x,
                  const float* __restrict__ Wo, const float* __restrict__ bo,
                  float* __restrict__ out) {
    const int n = blockIdx.x, t = threadIdx.x;
    __shared__ float ab[HEADS * 33];
    __shared__ float orow[DIM];
    for (int u = t; u < HEADS * 33; u += 128) ab[u] = acc[(size_t)n * HEADS * 33 + u];
    __syncthreads();
    const int col = t, hh = col >> 4, dd = col & 15;
    const float slv = ab[hh * 33];
    float acc2 = 0.f;
    #pragma unroll
    for (int e = 0; e < EDIM; ++e) acc2 = fmaf(ab[hh * 33 + 17 + e], Wve[e * DIM + col], acc2);
    orow[col] = (ab[hh * 33 + 1 + dd] + acc2) / slv + bve[col];
    __syncthreads();
    float o = bo[col] + x[(size_t)n * DIM + col];
    #pragma unroll 16
    for (int i = 0; i < DIM; ++i) o = fmaf(orow[i], Wo[i * DIM + col], o);
    out[(size_t)n * DIM + col] = o;
}

extern "C" void kernel_launch(void* const* d_in, const int* in_sizes, int n_in,
                              void* d_out, int out_size, void* d_ws, size_t ws_size,
                              hipStream_t stream) {
    const float* x     = (const float*)d_in[0];
    const float* ef    = (const float*)d_in[1];
    const int*   mask  = (const int*)d_in[2];
    const float* Wq    = (const float*)d_in[3];
    const float* bq    = (const float*)d_in[4];
    const float* Wk    = (const float*)d_in[5];
    const float* bk    = (const float*)d_in[6];
    const float* Wv    = (const float*)d_in[7];
    const float* bv    = (const float*)d_in[8];
    const float* Wae   = (const float*)d_in[9];
    const float* bae   = (const float*)d_in[10];
    const float* Wve   = (const float*)d_in[11];
    const float* bve   = (const float*)d_in[12];
    const float* Wo    = (const float*)d_in[13];
    const float* bo    = (const float*)d_in[14];
    const float* gamma = (const float*)d_in[15];
    const float* beta  = (const float*)d_in[16];

    float* ws = (float*)d_ws;
    float* accb = ws;                                   // 1024*8*33 = 270336 f32
    float* qg   = ws + 270336;
    float* kg   = qg + (size_t)NNODE * DIM;
    float* vg   = kg + (size_t)NNODE * DIM;

    hipMemsetAsync(accb, 0, (size_t)NNODE * HEADS * 33 * sizeof(float), stream);
    ln_qkv_kernel<<<NNODE, 384, 0, stream>>>(x, Wq, bq, Wk, bk, Wv, bv, gamma, beta, qg, kg, vg);
    attn_kernel<<<(NNODE / BN) * 32, 256, 0, stream>>>(qg, kg, vg, ef, mask, Wae, bae, accb);
    final_kernel<<<NNODE, 128, 0, stream>>>(accb, Wve, bve, x, Wo, bo, (float*)d_out);
}

// Round 8
// 200.376 us; speedup vs baseline: 2.6329x; 1.7734x over previous
//
#include <hip/hip_runtime.h>
#include <hip/hip_bf16.h>

#define NNODE 1024
#define DIM 128
#define HEADS 8
#define DK 16
#define EDIM 16
#define BN 8               // target nodes per attn block
#define MR 32              // source rows per block (one-shot, round-5 structure)
#define EF_ROW 20          // ef m-stride (dwords)
#define EF_NSTR 644        // ef n-stride = 32*20+4: bank skew +4 per n -> conflict-free
#define LOG2E 1.44269504f

// ---------------- Kernel 1: LayerNorm + QKV projection ----------------
__global__ __launch_bounds__(384)
void ln_qkv_kernel(const float* __restrict__ x,
                   const float* __restrict__ Wq, const float* __restrict__ bq,
                   const float* __restrict__ Wk, const float* __restrict__ bk,
                   const float* __restrict__ Wv, const float* __restrict__ bv,
                   const float* __restrict__ gamma, const float* __restrict__ beta,
                   float* __restrict__ qg, float* __restrict__ kg, float* __restrict__ vg) {
    const int n = blockIdx.x;
    const int t = threadIdx.x;
    __shared__ float hrow[DIM];
    __shared__ float part[4];

    float xv = 0.f;
    if (t < 128) {
        xv = x[n * DIM + t];
        float v = xv;
        #pragma unroll
        for (int off = 32; off >= 1; off >>= 1) v += __shfl_xor(v, off);
        if ((t & 63) == 0) part[t >> 6] = v;
    }
    __syncthreads();
    const float mu = (part[0] + part[1]) * (1.0f / DIM);
    const float dx = xv - mu;
    if (t < 128) {
        float v = dx * dx;
        #pragma unroll
        for (int off = 32; off >= 1; off >>= 1) v += __shfl_xor(v, off);
        if ((t & 63) == 0) part[2 + (t >> 6)] = v;
    }
    __syncthreads();
    if (t < 128) {
        const float var = (part[2] + part[3]) * (1.0f / DIM);
        hrow[t] = dx * rsqrtf(var + 1e-5f) * gamma[t] + beta[t];
    }
    __syncthreads();

    const int which = t >> 7;          // 0,1,2 -> q,k,v (wave-uniform)
    const int col = t & 127;
    const float* W = (which == 0) ? Wq : (which == 1) ? Wk : Wv;
    const float* b = (which == 0) ? bq : (which == 1) ? bk : bv;
    float* o       = (which == 0) ? qg : (which == 1) ? kg : vg;
    float acc = b[col];
    #pragma unroll 16
    for (int i = 0; i < DIM; ++i) acc = fmaf(hrow[i], W[i * DIM + col], acc);
    o[n * DIM + col] = acc;
}

// ---------------- Kernel 2: attention partials ----------------
// grid = (1024/BN)*32 = 4096 blocks; 256 threads = (s: t>>5, np: (t>>3)&3, h: t&7)
// Round-5 structure (one-shot staging, 64 us measured) with two changes:
//  * k/v are NOT staged in LDS: the 4 np-lanes of a wave read the same 64B k/v
//    segment and each row is read once per block -> L1-resident global loads.
//    LDS shrinks 63->22 KB (occupancy cap moves to VGPR) and the LDS pipe loses
//    its main consumer.
//  * reduction: 2 plain-write copies + 1 RMW step (NO LDS atomics - round 7
//    showed the shared-float atomicAdd path serializing the whole kernel).
__global__ __launch_bounds__(256, 2)
void attn_kernel(const float* __restrict__ qg, const float* __restrict__ kg,
                 const float* __restrict__ vg, const float* __restrict__ ef,
                 const int* __restrict__ mask,
                 const float* __restrict__ Wae, const float* __restrict__ bae,
                 float* __restrict__ acc) {
    const int t = threadIdx.x;
    const int s  = t >> 5;        // 0..7 m sub-slot
    const int np = (t >> 3) & 3;  // n-pair id
    const int h  = t & 7;         // head
    const int wid = t >> 6, lane = t & 63;
    const int bx = blockIdx.x;
    const int n0 = (bx >> 5) * BN;
    const int mb = (bx & 31) * MR;

    __shared__ float ef_lds[BN * EF_NSTR];   // 20.6 KB; overlaid by reduction scratch
    __shared__ int   mk_lds[BN * 34];        // 1.1 KB

    // --- ef stage: 1024 float4, 4 per thread, skewed layout (round-5 proven) ---
    #pragma unroll
    for (int r = 0; r < 4; ++r) {
        const int idx = t + 256 * r;            // 0..1023
        const int nn = idx >> 7;                // 0..7
        const int mm = (idx >> 2) & 31;
        const int q4 = idx & 3;
        const float4 ev = *(const float4*)(ef + ((size_t)(n0 + nn) * NNODE + mb + mm) * EDIM + q4 * 4);
        *(float4*)&ef_lds[nn * EF_NSTR + mm * EF_ROW + q4 * 4] = ev;
    }
    // --- mask stage: 8n x 32m, one per thread ---
    {
        const int nn = t >> 5, mm = t & 31;
        mk_lds[nn * 34 + mm] = mask[(size_t)(n0 + nn) * NNODE + (mb + mm)];
    }
    // --- per-thread constants (global, L2-hot) ---
    float qreg[2][DK];
    #pragma unroll
    for (int hf = 0; hf < 2; ++hf) {
        const float* qp = qg + (size_t)(n0 + np + 4 * hf) * DIM + h * DK;
        #pragma unroll
        for (int d4 = 0; d4 < 4; ++d4) {
            const float4 qv = *(const float4*)(qp + d4 * 4);
            qreg[hf][d4 * 4 + 0] = qv.x; qreg[hf][d4 * 4 + 1] = qv.y;
            qreg[hf][d4 * 4 + 2] = qv.z; qreg[hf][d4 * 4 + 3] = qv.w;
        }
    }
    float waec[EDIM];
    #pragma unroll
    for (int e = 0; e < EDIM; ++e) waec[e] = Wae[e * HEADS + h] * LOG2E;
    const float baeh = bae[h] * LOG2E;

    float sl[2] = {0.f, 0.f};
    float accv[2][DK], accT[2][EDIM];
    #pragma unroll
    for (int hf = 0; hf < 2; ++hf) {
        #pragma unroll
        for (int d = 0; d < DK; ++d) accv[hf][d] = 0.f;
        #pragma unroll
        for (int e = 0; e < EDIM; ++e) accT[hf][e] = 0.f;
    }

    __syncthreads();

    // --- compute: 4 m per thread (m = 8j+s); k/v straight from global (L1-hot).
    // unroll 1: keeps transient load regs from stacking across iterations (VGPR cap).
    #pragma unroll 1
    for (int j = 0; j < 4; ++j) {
        const int m = j * 8 + s;
        const size_t gm = (size_t)(mb + m);
        float kk[DK], vv[DK];
        const float* kp = kg + gm * DIM + h * DK;
        const float* vp = vg + gm * DIM + h * DK;
        #pragma unroll
        for (int d4 = 0; d4 < 4; ++d4) {
            const float4 k4 = *(const float4*)(kp + d4 * 4);
            kk[d4 * 4 + 0] = k4.x; kk[d4 * 4 + 1] = k4.y;
            kk[d4 * 4 + 2] = k4.z; kk[d4 * 4 + 3] = k4.w;
            const float4 v4 = *(const float4*)(vp + d4 * 4);
            vv[d4 * 4 + 0] = v4.x; vv[d4 * 4 + 1] = v4.y;
            vv[d4 * 4 + 2] = v4.z; vv[d4 * 4 + 3] = v4.w;
        }
        #pragma unroll
        for (int hf = 0; hf < 2; ++hf) {
            const int n = np + 4 * hf;
            const float* ep = &ef_lds[n * EF_NSTR + m * EF_ROW];
            float efv[EDIM];
            #pragma unroll
            for (int e4 = 0; e4 < 4; ++e4) {       // STATIC e4 (skew handles banks)
                const float4 ev = *(const float4*)(ep + e4 * 4);
                efv[e4 * 4 + 0] = ev.x; efv[e4 * 4 + 1] = ev.y;
                efv[e4 * 4 + 2] = ev.z; efv[e4 * 4 + 3] = ev.w;
            }
            float bias = baeh, dot = 0.f;
            #pragma unroll
            for (int e = 0; e < EDIM; ++e) bias = fmaf(efv[e], waec[e], bias);
            #pragma unroll
            for (int d = 0; d < DK; ++d) dot = fmaf(qreg[hf][d], kk[d], dot);
            const float lg = fmaf(dot, 0.25f * LOG2E, bias);
            const float p = mk_lds[n * 34 + m] ? __builtin_amdgcn_exp2f(lg) : 0.f;
            sl[hf] += p;
            #pragma unroll
            for (int d = 0; d < DK; ++d) accv[hf][d] = fmaf(p, vv[d], accv[hf][d]);
            #pragma unroll
            for (int e = 0; e < EDIM; ++e) accT[hf][e] = fmaf(p, efv[e], accT[hf][e]);
        }
    }

    // --- reduce s-pairs within wave (lane ^ 32) ---
    #pragma unroll
    for (int hf = 0; hf < 2; ++hf) {
        sl[hf] += __shfl_xor(sl[hf], 32);
        #pragma unroll
        for (int d = 0; d < DK; ++d) accv[hf][d] += __shfl_xor(accv[hf][d], 32);
        #pragma unroll
        for (int e = 0; e < EDIM; ++e) accT[hf][e] += __shfl_xor(accT[hf][e], 32);
    }
    __syncthreads();                  // all ef_lds reads done -> overlay scratch
    // Two 2112-f32 copies in the ef area. Write banks: addr=264n+33h+i -> bank
    // (8np+h+i)&31, distinct across the 32 active lanes: conflict-free.
    float* redA = ef_lds;
    float* redB = ef_lds + BN * HEADS * 33;
    if (lane < 32 && wid < 2) {       // waves 0,1: plain write
        float* base = (wid == 0) ? redA : redB;
        #pragma unroll
        for (int hf = 0; hf < 2; ++hf) {
            float* rp = base + ((np + 4 * hf) * 8 + h) * 33;
            rp[0] = sl[hf];
            #pragma unroll
            for (int d = 0; d < DK; ++d) rp[1 + d] = accv[hf][d];
            #pragma unroll
            for (int e = 0; e < EDIM; ++e) rp[17 + e] = accT[hf][e];
        }
    }
    __syncthreads();
    if (lane < 32 && wid >= 2) {      // waves 2,3: read-modify-write (plain ds ops)
        float* base = (wid == 2) ? redA : redB;
        #pragma unroll
        for (int hf = 0; hf < 2; ++hf) {
            float* rp = base + ((np + 4 * hf) * 8 + h) * 33;
            rp[0] += sl[hf];
            #pragma unroll
            for (int d = 0; d < DK; ++d) rp[1 + d] += accv[hf][d];
            #pragma unroll
            for (int e = 0; e < EDIM; ++e) rp[17 + e] += accT[hf][e];
        }
    }
    __syncthreads();
    // --- one global atomicAdd per reduced value ---
    for (int u = t; u < BN * HEADS * 33; u += 256)
        atomicAdd(&acc[(size_t)n0 * HEADS * 33 + u], redA[u] + redB[u]);
}

// ---------------- Kernel 3: epilogue (Wve, normalize, Wo, residual) ----------------
__global__ __launch_bounds__(128)
void final_kernel(const float* __restrict__ acc,
                  const float* __restrict__ Wve, const float* __restrict__ bve,
                  const float* __restrict__ x,
                  const float* __restrict__ Wo, const float* __restrict__ bo,
                  float* __restrict__ out) {
    const int n = blockIdx.x, t = threadIdx.x;
    __shared__ float ab[HEADS * 33];
    __shared__ float orow[DIM];
    for (int u = t; u < HEADS * 33; u += 128) ab[u] = acc[(size_t)n * HEADS * 33 + u];
    __syncthreads();
    const int col = t, hh = col >> 4, dd = col & 15;
    const float slv = ab[hh * 33];
    float acc2 = 0.f;
    #pragma unroll
    for (int e = 0; e < EDIM; ++e) acc2 = fmaf(ab[hh * 33 + 17 + e], Wve[e * DIM + col], acc2);
    orow[col] = (ab[hh * 33 + 1 + dd] + acc2) / slv + bve[col];
    __syncthreads();
    float o = bo[col] + x[(size_t)n * DIM + col];
    #pragma unroll 16
    for (int i = 0; i < DIM; ++i) o = fmaf(orow[i], Wo[i * DIM + col], o);
    out[(size_t)n * DIM + col] = o;
}

extern "C" void kernel_launch(void* const* d_in, const int* in_sizes, int n_in,
                              void* d_out, int out_size, void* d_ws, size_t ws_size,
                              hipStream_t stream) {
    const float* x     = (const float*)d_in[0];
    const float* ef    = (const float*)d_in[1];
    const int*   mask  = (const int*)d_in[2];
    const float* Wq    = (const float*)d_in[3];
    const float* bq    = (const float*)d_in[4];
    const float* Wk    = (const float*)d_in[5];
    const float* bk    = (const float*)d_in[6];
    const float* Wv    = (const float*)d_in[7];
    const float* bv    = (const float*)d_in[8];
    const float* Wae   = (const float*)d_in[9];
    const float* bae   = (const float*)d_in[10];
    const float* Wve   = (const float*)d_in[11];
    const float* bve   = (const float*)d_in[12];
    const float* Wo    = (const float*)d_in[13];
    const float* bo    = (const float*)d_in[14];
    const float* gamma = (const float*)d_in[15];
    const float* beta  = (const float*)d_in[16];

    float* ws = (float*)d_ws;
    float* accb = ws;                                   // 1024*8*33 = 270336 f32
    float* qg   = ws + 270336;
    float* kg   = qg + (size_t)NNODE * DIM;
    float* vg   = kg + (size_t)NNODE * DIM;

    hipMemsetAsync(accb, 0, (size_t)NNODE * HEADS * 33 * sizeof(float), stream);
    ln_qkv_kernel<<<NNODE, 384, 0, stream>>>(x, Wq, bq, Wk, bk, Wv, bv, gamma, beta, qg, kg, vg);
    attn_kernel<<<(NNODE / BN) * 32, 256, 0, stream>>>(qg, kg, vg, ef, mask, Wae, bae, accb);
    final_kernel<<<NNODE, 128, 0, stream>>>(accb, Wve, bve, x, Wo, bo, (float*)d_out);
}

// Round 9
// 191.142 us; speedup vs baseline: 2.7601x; 1.0483x over previous
//
#include <hip/hip_runtime.h>
#include <hip/hip_bf16.h>

#define NNODE 1024
#define DIM 128
#define HEADS 8
#define DK 16
#define EDIM 16
#define BN 8               // target nodes per attn block
#define MSPLIT 16          // m-range splits
#define MRANGE (NNODE / MSPLIT)   // 64 source rows per block
#define NJ (MRANGE / 8)    // 8 j-iterations (m = 8j + s)
#define LOG2E 1.44269504f

// ---------------- Kernel 1: LayerNorm + QKV projection ----------------
__global__ __launch_bounds__(384)
void ln_qkv_kernel(const float* __restrict__ x,
                   const float* __restrict__ Wq, const float* __restrict__ bq,
                   const float* __restrict__ Wk, const float* __restrict__ bk,
                   const float* __restrict__ Wv, const float* __restrict__ bv,
                   const float* __restrict__ gamma, const float* __restrict__ beta,
                   float* __restrict__ qg, float* __restrict__ kg, float* __restrict__ vg) {
    const int n = blockIdx.x;
    const int t = threadIdx.x;
    __shared__ float hrow[DIM];
    __shared__ float part[4];

    float xv = 0.f;
    if (t < 128) {
        xv = x[n * DIM + t];
        float v = xv;
        #pragma unroll
        for (int off = 32; off >= 1; off >>= 1) v += __shfl_xor(v, off);
        if ((t & 63) == 0) part[t >> 6] = v;
    }
    __syncthreads();
    const float mu = (part[0] + part[1]) * (1.0f / DIM);
    const float dx = xv - mu;
    if (t < 128) {
        float v = dx * dx;
        #pragma unroll
        for (int off = 32; off >= 1; off >>= 1) v += __shfl_xor(v, off);
        if ((t & 63) == 0) part[2 + (t >> 6)] = v;
    }
    __syncthreads();
    if (t < 128) {
        const float var = (part[2] + part[3]) * (1.0f / DIM);
        hrow[t] = dx * rsqrtf(var + 1e-5f) * gamma[t] + beta[t];
    }
    __syncthreads();

    const int which = t >> 7;          // 0,1,2 -> q,k,v (wave-uniform)
    const int col = t & 127;
    const float* W = (which == 0) ? Wq : (which == 1) ? Wk : Wv;
    const float* b = (which == 0) ? bq : (which == 1) ? bk : bv;
    float* o       = (which == 0) ? qg : (which == 1) ? kg : vg;
    float acc = b[col];
    #pragma unroll 16
    for (int i = 0; i < DIM; ++i) acc = fmaf(hrow[i], W[i * DIM + col], acc);
    o[n * DIM + col] = acc;
}

// ---------------- Kernel 2: attention partials, barrier-free main loop ----------------
// grid = (1024/BN)*MSPLIT = 2048 blocks; 256 threads = (s: t>>5, np: (t>>3)&3, h: t&7)
// NO LDS staging and NO barriers before the reduction tail: ef/k/v/mask are read
// straight from global. The 8 h-lanes of a (s,np) group read the SAME 64B ef/mask
// row (HW broadcast: no extra traffic), k/v rows are L2-resident. With zero
// barriers the compiler software-pipelines the fully-unrolled j-loop with
// fine-grained vmcnt waits, so ef stream latency overlaps compute (rounds 5-8
// showed the staging barrier serializing fetch->compute at 2 blocks/CU).
// __launch_bounds__(256,2): empirically VGPR budget = 256/N; N=2 fits the ~114
// floats of live state (round 6: N=4 clamped to 64 VGPR -> 1.15 GB spills).
__global__ __launch_bounds__(256, 2)
void attn_kernel(const float* __restrict__ qg, const float* __restrict__ kg,
                 const float* __restrict__ vg, const float* __restrict__ ef,
                 const int* __restrict__ mask,
                 const float* __restrict__ Wae, const float* __restrict__ bae,
                 float* __restrict__ acc) {
    const int t = threadIdx.x;
    const int s  = t >> 5;        // 0..7 m sub-slot
    const int np = (t >> 3) & 3;  // n-pair id
    const int h  = t & 7;         // head
    const int wid = t >> 6, lane = t & 63;
    const int bx = blockIdx.x;
    const int n0 = (bx >> 4) * BN;            // 16 ms-splits per node-group
    const int mb = (bx & 15) * MRANGE;

    __shared__ float red2[2 * BN * HEADS * 33];   // 16.9 KB reduction scratch only

    // --- per-thread constants (global, L2-hot) ---
    float qreg[2][DK];
    #pragma unroll
    for (int hf = 0; hf < 2; ++hf) {
        const float* qp = qg + (size_t)(n0 + np + 4 * hf) * DIM + h * DK;
        #pragma unroll
        for (int d4 = 0; d4 < 4; ++d4) {
            const float4 qv = *(const float4*)(qp + d4 * 4);
            qreg[hf][d4 * 4 + 0] = qv.x; qreg[hf][d4 * 4 + 1] = qv.y;
            qreg[hf][d4 * 4 + 2] = qv.z; qreg[hf][d4 * 4 + 3] = qv.w;
        }
    }
    float waec[EDIM];
    #pragma unroll
    for (int e = 0; e < EDIM; ++e) waec[e] = Wae[e * HEADS + h] * LOG2E;
    const float baeh = bae[h] * LOG2E;

    float sl[2] = {0.f, 0.f};
    float accv[2][DK], accT[2][EDIM];
    #pragma unroll
    for (int hf = 0; hf < 2; ++hf) {
        #pragma unroll
        for (int d = 0; d < DK; ++d) accv[hf][d] = 0.f;
        #pragma unroll
        for (int e = 0; e < EDIM; ++e) accT[hf][e] = 0.f;
    }

    // --- main loop: 8 m per thread (m = 8j+s), n-pair per m; everything global ---
    #pragma unroll 2
    for (int j = 0; j < NJ; ++j) {
        const int gm = mb + j * 8 + s;
        float kk[DK], vv[DK];
        const float* kp = kg + (size_t)gm * DIM + h * DK;
        const float* vp = vg + (size_t)gm * DIM + h * DK;
        #pragma unroll
        for (int d4 = 0; d4 < 4; ++d4) {
            const float4 k4 = *(const float4*)(kp + d4 * 4);
            kk[d4 * 4 + 0] = k4.x; kk[d4 * 4 + 1] = k4.y;
            kk[d4 * 4 + 2] = k4.z; kk[d4 * 4 + 3] = k4.w;
            const float4 v4 = *(const float4*)(vp + d4 * 4);
            vv[d4 * 4 + 0] = v4.x; vv[d4 * 4 + 1] = v4.y;
            vv[d4 * 4 + 2] = v4.z; vv[d4 * 4 + 3] = v4.w;
        }
        #pragma unroll
        for (int hf = 0; hf < 2; ++hf) {
            const int n = np + 4 * hf;
            const float* ep = ef + ((size_t)(n0 + n) * NNODE + gm) * EDIM;
            float efv[EDIM];
            #pragma unroll
            for (int e4 = 0; e4 < 4; ++e4) {
                const float4 ev = *(const float4*)(ep + e4 * 4);   // 8-lane broadcast
                efv[e4 * 4 + 0] = ev.x; efv[e4 * 4 + 1] = ev.y;
                efv[e4 * 4 + 2] = ev.z; efv[e4 * 4 + 3] = ev.w;
            }
            const int mk = mask[(size_t)(n0 + n) * NNODE + gm];
            float bias = baeh, dot = 0.f;
            #pragma unroll
            for (int e = 0; e < EDIM; ++e) bias = fmaf(efv[e], waec[e], bias);
            #pragma unroll
            for (int d = 0; d < DK; ++d) dot = fmaf(qreg[hf][d], kk[d], dot);
            const float lg = fmaf(dot, 0.25f * LOG2E, bias);
            const float p = mk ? __builtin_amdgcn_exp2f(lg) : 0.f;  // masked == exact 0, as ref
            sl[hf] += p;
            #pragma unroll
            for (int d = 0; d < DK; ++d) accv[hf][d] = fmaf(p, vv[d], accv[hf][d]);
            #pragma unroll
            for (int e = 0; e < EDIM; ++e) accT[hf][e] = fmaf(p, efv[e], accT[hf][e]);
        }
    }

    // --- reduce s-pairs within wave (lane ^ 32) ---
    #pragma unroll
    for (int hf = 0; hf < 2; ++hf) {
        sl[hf] += __shfl_xor(sl[hf], 32);
        #pragma unroll
        for (int d = 0; d < DK; ++d) accv[hf][d] += __shfl_xor(accv[hf][d], 32);
        #pragma unroll
        for (int e = 0; e < EDIM; ++e) accT[hf][e] += __shfl_xor(accT[hf][e], 32);
    }
    // Two 2112-f32 copies. Write banks: addr=264n+33h+i -> bank (8np+h+i)&31,
    // distinct across the 32 active lanes: conflict-free. NO LDS atomics
    // (round 7: shared-float atomicAdd serialized the kernel).
    float* redA = red2;
    float* redB = red2 + BN * HEADS * 33;
    if (lane < 32 && wid < 2) {       // waves 0,1: plain write
        float* base = (wid == 0) ? redA : redB;
        #pragma unroll
        for (int hf = 0; hf < 2; ++hf) {
            float* rp = base + ((np + 4 * hf) * 8 + h) * 33;
            rp[0] = sl[hf];
            #pragma unroll
            for (int d = 0; d < DK; ++d) rp[1 + d] = accv[hf][d];
            #pragma unroll
            for (int e = 0; e < EDIM; ++e) rp[17 + e] = accT[hf][e];
        }
    }
    __syncthreads();
    if (lane < 32 && wid >= 2) {      // waves 2,3: read-modify-write (plain ds ops)
        float* base = (wid == 2) ? redA : redB;
        #pragma unroll
        for (int hf = 0; hf < 2; ++hf) {
            float* rp = base + ((np + 4 * hf) * 8 + h) * 33;
            rp[0] += sl[hf];
            #pragma unroll
            for (int d = 0; d < DK; ++d) rp[1 + d] += accv[hf][d];
            #pragma unroll
            for (int e = 0; e < EDIM; ++e) rp[17 + e] += accT[hf][e];
        }
    }
    __syncthreads();
    // --- one global atomicAdd per reduced value (16 contending blocks per n0) ---
    for (int u = t; u < BN * HEADS * 33; u += 256)
        atomicAdd(&acc[(size_t)n0 * HEADS * 33 + u], redA[u] + redB[u]);
}

// ---------------- Kernel 3: epilogue (Wve, normalize, Wo, residual) ----------------
__global__ __launch_bounds__(128)
void final_kernel(const float* __restrict__ acc,
                  const float* __restrict__ Wve, const float* __restrict__ bve,
                  const float* __restrict__ x,
                  const float* __restrict__ Wo, const float* __restrict__ bo,
                  float* __restrict__ out) {
    const int n = blockIdx.x, t = threadIdx.x;
    __shared__ float ab[HEADS * 33];
    __shared__ float orow[DIM];
    for (int u = t; u < HEADS * 33; u += 128) ab[u] = acc[(size_t)n * HEADS * 33 + u];
    __syncthreads();
    const int col = t, hh = col >> 4, dd = col & 15;
    const float slv = ab[hh * 33];
    float acc2 = 0.f;
    #pragma unroll
    for (int e = 0; e < EDIM; ++e) acc2 = fmaf(ab[hh * 33 + 17 + e], Wve[e * DIM + col], acc2);
    orow[col] = (ab[hh * 33 + 1 + dd] + acc2) / slv + bve[col];
    __syncthreads();
    float o = bo[col] + x[(size_t)n * DIM + col];
    #pragma unroll 16
    for (int i = 0; i < DIM; ++i) o = fmaf(orow[i], Wo[i * DIM + col], o);
    out[(size_t)n * DIM + col] = o;
}

extern "C" void kernel_launch(void* const* d_in, const int* in_sizes, int n_in,
                              void* d_out, int out_size, void* d_ws, size_t ws_size,
                              hipStream_t stream) {
    const float* x     = (const float*)d_in[0];
    const float* ef    = (const float*)d_in[1];
    const int*   mask  = (const int*)d_in[2];
    const float* Wq    = (const float*)d_in[3];
    const float* bq    = (const float*)d_in[4];
    const float* Wk    = (const float*)d_in[5];
    const float* bk    = (const float*)d_in[6];
    const float* Wv    = (const float*)d_in[7];
    const float* bv    = (const float*)d_in[8];
    const float* Wae   = (const float*)d_in[9];
    const float* bae   = (const float*)d_in[10];
    const float* Wve   = (const float*)d_in[11];
    const float* bve   = (const float*)d_in[12];
    const float* Wo    = (const float*)d_in[13];
    const float* bo    = (const float*)d_in[14];
    const float* gamma = (const float*)d_in[15];
    const float* beta  = (const float*)d_in[16];

    float* ws = (float*)d_ws;
    float* accb = ws;                                   // 1024*8*33 = 270336 f32
    float* qg   = ws + 270336;
    float* kg   = qg + (size_t)NNODE * DIM;
    float* vg   = kg + (size_t)NNODE * DIM;

    hipMemsetAsync(accb, 0, (size_t)NNODE * HEADS * 33 * sizeof(float), stream);
    ln_qkv_kernel<<<NNODE, 384, 0, stream>>>(x, Wq, bq, Wk, bk, Wv, bv, gamma, beta, qg, kg, vg);
    attn_kernel<<<(NNODE / BN) * MSPLIT, 256, 0, stream>>>(qg, kg, vg, ef, mask, Wae, bae, accb);
    final_kernel<<<NNODE, 128, 0, stream>>>(accb, Wve, bve, x, Wo, bo, (float*)d_out);
}